// Round 2
// baseline (3289.286 us; speedup 1.0000x reference)
//
#include <hip/hip_runtime.h>
#include <stdint.h>

// ======================= types & helpers =======================
typedef short short8 __attribute__((ext_vector_type(8)));
typedef float f32x4 __attribute__((ext_vector_type(4)));

#define DEVI static __device__ __forceinline__

DEVI float b2f(unsigned short u) {
  union { float f; uint32_t i; } v; v.i = ((uint32_t)u) << 16; return v.f;
}
DEVI unsigned short f2b(float f) {  // RNE f32 -> bf16
  union { float f; uint32_t i; } v; v.f = f;
  uint32_t r = v.i + 0x7FFFu + ((v.i >> 16) & 1u);
  return (unsigned short)(r >> 16);
}

// async global->LDS, 16B per lane (HW: LDS dest = wave base + lane*16)
DEVI void async_cp16(const unsigned short* g, unsigned short* l) {
  __builtin_amdgcn_global_load_lds(
      (const __attribute__((address_space(1))) void*)g,
      (__attribute__((address_space(3))) void*)l, 16, 0, 0);
}

// ======================= kernels =======================

// f32 -> bf16 convert, 4 elems/thread, grid*256*4 == n exactly
__global__ __launch_bounds__(256) void cvt_f32_bf16(
    const float4* __restrict__ src, unsigned short* __restrict__ dst) {
  const int i = blockIdx.x * 256 + threadIdx.x;
  float4 f = src[i];
  uint2 o;
  o.x = (uint32_t)f2b(f.x) | ((uint32_t)f2b(f.y) << 16);
  o.y = (uint32_t)f2b(f.z) | ((uint32_t)f2b(f.w) << 16);
  ((uint2*)dst)[i] = o;
}

// f32 [R,C] -> bf16 [C,R] tiled transpose+convert
__global__ __launch_bounds__(256) void wtrans(
    const float* __restrict__ src, unsigned short* __restrict__ dst, int R, int C) {
  __shared__ float tile[32][33];
  const int tx = threadIdx.x & 31, ty = threadIdx.x >> 5;
  const int c0 = blockIdx.x * 32, r0 = blockIdx.y * 32;
#pragma unroll
  for (int i = 0; i < 32; i += 8)
    tile[ty + i][tx] = src[(long)(r0 + ty + i) * C + c0 + tx];
  __syncthreads();
#pragma unroll
  for (int i = 0; i < 32; i += 8)
    dst[(long)(c0 + ty + i) * R + r0 + tx] = f2b(tile[tx][ty + i]);
}

// V [rb][t][h][d] (bf16, row pitch 4096) -> Vt [rb*8+h][d][t]  (z = rb*8+h)
__global__ __launch_bounds__(256) void vtrans(
    const unsigned short* __restrict__ V, unsigned short* __restrict__ Vt) {
  __shared__ unsigned short tile[32][33];
  const int z = blockIdx.z, b = z >> 3, h = z & 7;
  const int tc = blockIdx.x;  // d tile (16)
  const int tr = blockIdx.y;  // t tile (32)
  const int tx = threadIdx.x & 31, ty = threadIdx.x >> 5;
  const unsigned short* s = V + (long)b * 4194304 + (long)h * 512;
#pragma unroll
  for (int i = 0; i < 32; i += 8)
    tile[ty + i][tx] = s[(long)(tr * 32 + ty + i) * 4096 + tc * 32 + tx];
  __syncthreads();
  unsigned short* d = Vt + (long)z * 524288;
#pragma unroll
  for (int i = 0; i < 32; i += 8)
    d[(long)(tc * 32 + ty + i) * 1024 + tr * 32 + tx] = tile[tx][ty + i];
}

// in-place softmax over rows of 1024 bf16 (one block per row)
__global__ __launch_bounds__(256) void softmax_rows(unsigned short* __restrict__ S) {
  const int tid = threadIdx.x;
  unsigned short* p = S + (long)blockIdx.x * 1024;
  float v[4];
  float m = -3.0e38f;
#pragma unroll
  for (int i = 0; i < 4; i++) { v[i] = b2f(p[tid + 256 * i]); m = fmaxf(m, v[i]); }
#pragma unroll
  for (int o = 1; o < 64; o <<= 1) m = fmaxf(m, __shfl_xor(m, o));
  __shared__ float rm[4], rsum[4];
  const int lane = tid & 63, wave = tid >> 6;
  if (lane == 0) rm[wave] = m;
  __syncthreads();
  m = fmaxf(fmaxf(rm[0], rm[1]), fmaxf(rm[2], rm[3]));
  float s = 0.f;
#pragma unroll
  for (int i = 0; i < 4; i++) { v[i] = __expf(v[i] - m); s += v[i]; }
#pragma unroll
  for (int o = 1; o < 64; o <<= 1) s += __shfl_xor(s, o);
  if (lane == 0) rsum[wave] = s;
  __syncthreads();
  s = rsum[0] + rsum[1] + rsum[2] + rsum[3];
  const float inv = 1.f / s;
#pragma unroll
  for (int i = 0; i < 4; i++) p[tid + 256 * i] = f2b(v[i] * inv);
}

// LayerNorm over rows of 512 f32; Y (f32, optional) and Yb (bf16, optional).
// NOTE: X and Y may alias (in-place): all reads of the row complete before writes.
__global__ __launch_bounds__(256) void layernorm_rows(
    const float* X, const float* __restrict__ g,
    const float* __restrict__ b, float* Y,
    unsigned short* __restrict__ Yb) {
  const int tid = threadIdx.x;
  const long row = blockIdx.x;
  const float* x = X + row * 512;
  float v0 = x[tid], v1 = x[tid + 256];
  float s1 = v0 + v1;
  float s2 = v0 * v0 + v1 * v1;
#pragma unroll
  for (int o = 1; o < 64; o <<= 1) {
    s1 += __shfl_xor(s1, o);
    s2 += __shfl_xor(s2, o);
  }
  __shared__ float r1[4], r2[4];
  const int lane = tid & 63, wave = tid >> 6;
  if (lane == 0) { r1[wave] = s1; r2[wave] = s2; }
  __syncthreads();
  s1 = r1[0] + r1[1] + r1[2] + r1[3];
  s2 = r2[0] + r2[1] + r2[2] + r2[3];
  const float mu = s1 * (1.f / 512.f);
  const float var = s2 * (1.f / 512.f) - mu * mu;
  const float rs = rsqrtf(var + 1e-5f);
  float y0 = (v0 - mu) * rs * g[tid] + b[tid];
  float y1 = (v1 - mu) * rs * g[tid + 256] + b[tid + 256];
  if (Y) { Y[row * 512 + tid] = y0; Y[row * 512 + tid + 256] = y1; }
  if (Yb) { Yb[row * 512 + tid] = f2b(y0); Yb[row * 512 + tid + 256] = f2b(y1); }
}

// ======================= the GEMM =======================
// C[M,N] = A[M,K] @ B[N,K]^T, bf16 in, fp32 acc. 128x128 tile, BK=32,
// 256 thr = 4 waves in 2x2, each wave 64x64 via 4x4 of mfma_16x16x32_bf16.
// Batched via blockIdx.z: per-matrix offset = (z>>3)*sb + (z&7)*sh  (elements).
// EPI: 0 = bf16 out *scale;
//      1 = f32 out + optional bias[n] + optional res (may ALIAS C, same index);
//      2 = bf16 out, relu(acc + bias[n]).
template <int EPI>
__global__ __launch_bounds__(256, 2) void gemm_bt(
    const unsigned short* __restrict__ A, int lda, long asb, long ash,
    const unsigned short* __restrict__ B, int ldb, long bsb, long bsh,
    void* Cv, int ldc, long csb, long csh,
    int K, float scale,
    const float* __restrict__ bias, const float* res) {
  __shared__ __align__(16) unsigned short As[128 * 32];
  __shared__ __align__(16) unsigned short Bs[128 * 32];
  const int tid = threadIdx.x;
  const int lane = tid & 63;
  const int wave = tid >> 6;
  const int zb = (int)(blockIdx.z >> 3), zh = (int)(blockIdx.z & 7);
  const int m0 = blockIdx.y * 128;
  const int n0 = blockIdx.x * 128;

  const unsigned short* Ab = A + zb * asb + zh * ash + (long)m0 * lda;
  const unsigned short* Bb = B + zb * bsb + zh * bsh + (long)n0 * ldb;

  const int r0 = tid >> 2;           // staging row (0..63)
  const int p0 = (tid & 3) << 3;     // staging 8-elem chunk within BK=32

  f32x4 acc[4][4];
#pragma unroll
  for (int i = 0; i < 4; i++)
#pragma unroll
    for (int j = 0; j < 4; j++) acc[i][j] = (f32x4){0.f, 0.f, 0.f, 0.f};

  const int wm = (wave >> 1) << 6;
  const int wn = (wave & 1) << 6;
  const int fm = lane & 15;
  const int k8 = (lane >> 4) << 3;

  for (int kt = 0; kt < K; kt += 32) {
    __syncthreads();
    async_cp16(Ab + (long)r0 * lda + kt + p0, &As[tid * 8]);
    async_cp16(Ab + (long)(r0 + 64) * lda + kt + p0, &As[2048 + tid * 8]);
    async_cp16(Bb + (long)r0 * ldb + kt + p0, &Bs[tid * 8]);
    async_cp16(Bb + (long)(r0 + 64) * ldb + kt + p0, &Bs[2048 + tid * 8]);
    __syncthreads();

    short8 af[4], bfr[4];
#pragma unroll
    for (int i = 0; i < 4; i++)
      af[i] = *(const short8*)&As[(wm + i * 16 + fm) * 32 + k8];
#pragma unroll
    for (int j = 0; j < 4; j++)
      bfr[j] = *(const short8*)&Bs[(wn + j * 16 + fm) * 32 + k8];
#pragma unroll
    for (int i = 0; i < 4; i++)
#pragma unroll
      for (int j = 0; j < 4; j++)
        acc[i][j] = __builtin_amdgcn_mfma_f32_16x16x32_bf16(af[i], bfr[j], acc[i][j], 0, 0, 0);
  }

  // epilogue: D row=(lane>>4)*4+reg, col=lane&15 within each 16x16 tile
  const long coff = zb * csb + zh * csh;
  const int er = (lane >> 4) << 2;
  const int ec = lane & 15;
#pragma unroll
  for (int i = 0; i < 4; i++) {
#pragma unroll
    for (int j = 0; j < 4; j++) {
      const int gc = n0 + wn + j * 16 + ec;
#pragma unroll
      for (int r = 0; r < 4; r++) {
        const int gr = m0 + wm + i * 16 + er + r;
        const float v = acc[i][j][r];
        const long idx = coff + (long)gr * ldc + gc;
        if constexpr (EPI == 0) {
          ((unsigned short*)Cv)[idx] = f2b(v * scale);
        } else if constexpr (EPI == 1) {
          float o = v;
          if (bias) o += bias[gc];
          if (res) o += res[(long)gr * ldc + gc];
          ((float*)Cv)[idx] = o;
        } else {
          ((unsigned short*)Cv)[idx] = f2b(fmaxf(v + bias[gc], 0.f));
        }
      }
    }
  }
}

// ======================= launch =======================
extern "C" void kernel_launch(void* const* d_in, const int* in_sizes, int n_in,
                              void* d_out, int out_size, void* d_ws, size_t ws_size,
                              hipStream_t stream) {
  const float* x     = (const float*)d_in[0];
  const float* enc   = (const float*)d_in[1];
  const float* ln1_g = (const float*)d_in[10];
  const float* ln1_b = (const float*)d_in[11];
  const float* ln2_g = (const float*)d_in[12];
  const float* ln2_b = (const float*)d_in[13];
  const float* ln3_g = (const float*)d_in[14];
  const float* ln3_b = (const float*)d_in[15];
  const float* ff_b1 = (const float*)d_in[17];
  const float* ff_b2 = (const float*)d_in[19];

  uint8_t* ws = (uint8_t*)d_ws;
  auto US = [&](size_t o) { return (unsigned short*)(ws + o); };
  auto F  = [&](size_t o) { return (float*)(ws + o); };

  const size_t MB = 1ull << 20;
  const size_t SZ_WBIG = 4 * MB, SZ_WFF = 2 * MB;

  // ---- common region: inputs bf16 + weights bf16 (52 MB) ----
  const size_t O_XB = 0, O_ENCB = 8 * MB, O_WT = 16 * MB;  // WT: 36 MB -> 52 MB
  auto WT = [&](int i) { return US(O_WT + (size_t)i * SZ_WBIG); };  // i<9; ff_w2 special

  // ---- adaptive layout ----
  // mode A (full projections): fixed 268 MB + CB*24 MB, CB in {8,4,2,1}
  // mode B (per-b everything): 124 MB
  const size_t fixedA = 268 * MB;
  int CB = 0;
  for (int c = 8; c >= 1; c >>= 1)
    if (fixedA + (size_t)c * 24 * MB <= ws_size) { CB = c; break; }
  const bool modeA = (CB != 0);

  // mode A regions
  const size_t A_Q = 52 * MB, A_K = 116 * MB, A_V = 180 * MB,
               A_RES = 244 * MB, A_XNB = 260 * MB, A_VT = 268 * MB;
  const size_t A_S = A_VT + (size_t)(modeA ? CB : 1) * 8 * MB;
  // mode B regions
  const size_t B_RES = 52 * MB, B_XNB = 68 * MB, B_Qb = 76 * MB, B_Kb = 84 * MB,
               B_Vb = 92 * MB, B_VTb = 100 * MB, B_Sb = 108 * MB;  // -> 124 MB

  const size_t O_RES = modeA ? A_RES : B_RES;
  const size_t O_XNB = modeA ? A_XNB : B_XNB;
  const size_t O_H   = modeA ? A_K : B_Qb;  // FF hidden (32 MB), reuses dead region

  const float qsc = 0.21022410381342863f;  // 512^-0.25
  dim3 B256(256);

  // input converts
  cvt_f32_bf16<<<4096, B256, 0, stream>>>((const float4*)x, US(O_XB));
  cvt_f32_bf16<<<4096, B256, 0, stream>>>((const float4*)enc, US(O_ENCB));

  // weight transpose+convert: W[R,C] f32 -> W^T[C,R] bf16
  struct WSpec { const float* s; size_t off; int R, C; };
  const WSpec wspec[10] = {
      {(const float*)d_in[2], O_WT + 0 * SZ_WBIG, 512, 4096},   // sa_wq
      {(const float*)d_in[3], O_WT + 1 * SZ_WBIG, 512, 4096},   // sa_wk
      {(const float*)d_in[4], O_WT + 2 * SZ_WBIG, 512, 4096},   // sa_wv
      {(const float*)d_in[5], O_WT + 3 * SZ_WBIG, 4096, 512},   // sa_wo
      {(const float*)d_in[6], O_WT + 4 * SZ_WBIG, 512, 4096},   // ca_wq
      {(const float*)d_in[7], O_WT + 5 * SZ_WBIG, 512, 4096},   // ca_wk
      {(const float*)d_in[8], O_WT + 6 * SZ_WBIG, 512, 4096},   // ca_wv
      {(const float*)d_in[9], O_WT + 7 * SZ_WBIG, 4096, 512},   // ca_wo
      {(const float*)d_in[16], O_WT + 8 * SZ_WBIG, 512, 2048},  // ff_w1
      {(const float*)d_in[18], O_WT + 8 * SZ_WBIG + SZ_WFF, 2048, 512},  // ff_w2
  };
  for (int i = 0; i < 10; i++)
    wtrans<<<dim3(wspec[i].C / 32, wspec[i].R / 32), B256, 0, stream>>>(
        wspec[i].s, US(wspec[i].off), wspec[i].R, wspec[i].C);

  // ---- mode A attention: full projections, attention core chunked over batch ----
  auto attentionA = [&](const unsigned short* qsrc, const unsigned short* kvsrc,
                        int wb, const float* resid) {
    gemm_bt<0><<<dim3(32, 64, 1), B256, 0, stream>>>(
        qsrc, 512, 0, 0, WT(wb + 0), 512, 0, 0, US(A_Q), 4096, 0, 0, 512, qsc, nullptr, nullptr);
    gemm_bt<0><<<dim3(32, 64, 1), B256, 0, stream>>>(
        kvsrc, 512, 0, 0, WT(wb + 1), 512, 0, 0, US(A_K), 4096, 0, 0, 512, qsc, nullptr, nullptr);
    gemm_bt<0><<<dim3(32, 64, 1), B256, 0, stream>>>(
        kvsrc, 512, 0, 0, WT(wb + 2), 512, 0, 0, US(A_V), 4096, 0, 0, 512, 1.f, nullptr, nullptr);
    for (int c = 0; c < 8 / CB; c++) {
      const long bo = (long)c * CB * 4194304L;
      vtrans<<<dim3(16, 32, CB * 8), B256, 0, stream>>>(US(A_V) + bo, US(A_VT));
      gemm_bt<0><<<dim3(8, 8, CB * 8), B256, 0, stream>>>(
          US(A_Q) + bo, 4096, 4194304L, 512L, US(A_K) + bo, 4096, 4194304L, 512L,
          US(A_S), 1024, 8388608L, 1048576L, 512, 1.f, nullptr, nullptr);
      softmax_rows<<<CB * 8192, B256, 0, stream>>>(US(A_S));
      // O overwrites Q rows of this chunk (Q dead after QK^T of the chunk)
      gemm_bt<0><<<dim3(4, 8, CB * 8), B256, 0, stream>>>(
          US(A_S), 1024, 8388608L, 1048576L, US(A_VT), 1024, 4194304L, 524288L,
          US(A_Q) + bo, 4096, 4194304L, 512L, 1024, 1.f, nullptr, nullptr);
    }
    gemm_bt<1><<<dim3(4, 64, 1), B256, 0, stream>>>(
        US(A_Q), 4096, 0, 0, WT(wb + 3), 4096, 0, 0,
        F(O_RES), 512, 0, 0, 4096, 1.f, nullptr, resid);
  };

  // ---- mode B attention: everything per batch (124 MB workspace) ----
  auto attentionB = [&](const unsigned short* qsrc, const unsigned short* kvsrc,
                        int wb, const float* resid) {
    for (int b = 0; b < 8; b++) {
      const unsigned short* qb = qsrc + (long)b * 524288;
      const unsigned short* kb = kvsrc + (long)b * 524288;
      gemm_bt<0><<<dim3(32, 8, 1), B256, 0, stream>>>(
          qb, 512, 0, 0, WT(wb + 0), 512, 0, 0, US(B_Qb), 4096, 0, 0, 512, qsc, nullptr, nullptr);
      gemm_bt<0><<<dim3(32, 8, 1), B256, 0, stream>>>(
          kb, 512, 0, 0, WT(wb + 1), 512, 0, 0, US(B_Kb), 4096, 0, 0, 512, qsc, nullptr, nullptr);
      gemm_bt<0><<<dim3(32, 8, 1), B256, 0, stream>>>(
          kb, 512, 0, 0, WT(wb + 2), 512, 0, 0, US(B_Vb), 4096, 0, 0, 512, 1.f, nullptr, nullptr);
      vtrans<<<dim3(16, 32, 8), B256, 0, stream>>>(US(B_Vb), US(B_VTb));
      gemm_bt<0><<<dim3(8, 8, 8), B256, 0, stream>>>(
          US(B_Qb), 4096, 0, 512L, US(B_Kb), 4096, 0, 512L,
          US(B_Sb), 1024, 0, 1048576L, 512, 1.f, nullptr, nullptr);
      softmax_rows<<<8192, B256, 0, stream>>>(US(B_Sb));
      gemm_bt<0><<<dim3(4, 8, 8), B256, 0, stream>>>(
          US(B_Sb), 1024, 0, 1048576L, US(B_VTb), 1024, 0, 524288L,
          US(B_Qb), 4096, 0, 512L, 1024, 1.f, nullptr, nullptr);
      gemm_bt<1><<<dim3(4, 8, 1), B256, 0, stream>>>(
          US(B_Qb), 4096, 0, 0, WT(wb + 3), 4096, 0, 0,
          F(O_RES) + (long)b * 524288, 512, 0, 0, 4096, 1.f, nullptr,
          resid + (long)b * 524288);
    }
  };

  auto attention = [&](const unsigned short* q, const unsigned short* kv, int wb,
                       const float* r) {
    if (modeA) attentionA(q, kv, wb, r); else attentionB(q, kv, wb, r);
  };

  // self-attention + LN1 (RES in-place)
  attention(US(O_XB), US(O_XB), 0, x);
  layernorm_rows<<<8192, B256, 0, stream>>>(F(O_RES), ln1_g, ln1_b, F(O_RES), US(O_XNB));
  // cross-attention + LN2
  attention(US(O_XNB), US(O_ENCB), 4, F(O_RES));
  layernorm_rows<<<8192, B256, 0, stream>>>(F(O_RES), ln2_g, ln2_b, F(O_RES), US(O_XNB));
  // FF: relu(x2 @ w1 + b1) @ w2 + b2 + x2, then LN3 -> d_out
  gemm_bt<2><<<dim3(16, 64, 1), B256, 0, stream>>>(
      US(O_XNB), 512, 0, 0, WT(8), 512, 0, 0,
      US(O_H), 2048, 0, 0, 512, 1.f, ff_b1, nullptr);
  gemm_bt<1><<<dim3(4, 64, 1), B256, 0, stream>>>(
      US(O_H), 2048, 0, 0, US(O_WT + 8 * SZ_WBIG + SZ_WFF), 2048, 0, 0,
      F(O_RES), 512, 0, 0, 2048, 1.f, ff_b2, F(O_RES));
  layernorm_rows<<<8192, B256, 0, stream>>>(F(O_RES), ln3_g, ln3_b, (float*)d_out, nullptr);
}

// Round 3
// 2021.756 us; speedup vs baseline: 1.6269x; 1.6269x over previous
//
#include <hip/hip_runtime.h>
#include <stdint.h>

// ======================= types & helpers =======================
typedef short short8 __attribute__((ext_vector_type(8)));
typedef float f32x4 __attribute__((ext_vector_type(4)));

#define DEVI static __device__ __forceinline__

DEVI float b2f(unsigned short u) {
  union { float f; uint32_t i; } v; v.i = ((uint32_t)u) << 16; return v.f;
}
DEVI unsigned short f2b(float f) {  // RNE f32 -> bf16
  union { float f; uint32_t i; } v; v.f = f;
  uint32_t r = v.i + 0x7FFFu + ((v.i >> 16) & 1u);
  return (unsigned short)(r >> 16);
}

// async global->LDS, 16B per lane (HW: LDS dest = wave base + lane*16)
DEVI void async_cp16(const unsigned short* g, unsigned short* l) {
  __builtin_amdgcn_global_load_lds(
      (const __attribute__((address_space(1))) void*)g,
      (__attribute__((address_space(3))) void*)l, 16, 0, 0);
}

// ======================= kernels =======================

// f32 -> bf16 convert, 4 elems/thread, grid*256*4 == n exactly
__global__ __launch_bounds__(256) void cvt_f32_bf16(
    const float4* __restrict__ src, unsigned short* __restrict__ dst) {
  const int i = blockIdx.x * 256 + threadIdx.x;
  float4 f = src[i];
  uint2 o;
  o.x = (uint32_t)f2b(f.x) | ((uint32_t)f2b(f.y) << 16);
  o.y = (uint32_t)f2b(f.z) | ((uint32_t)f2b(f.w) << 16);
  ((uint2*)dst)[i] = o;
}

// f32 [R,C] -> bf16 [C,R] tiled transpose+convert
__global__ __launch_bounds__(256) void wtrans(
    const float* __restrict__ src, unsigned short* __restrict__ dst, int R, int C) {
  __shared__ float tile[32][33];
  const int tx = threadIdx.x & 31, ty = threadIdx.x >> 5;
  const int c0 = blockIdx.x * 32, r0 = blockIdx.y * 32;
#pragma unroll
  for (int i = 0; i < 32; i += 8)
    tile[ty + i][tx] = src[(long)(r0 + ty + i) * C + c0 + tx];
  __syncthreads();
#pragma unroll
  for (int i = 0; i < 32; i += 8)
    dst[(long)(c0 + ty + i) * R + r0 + tx] = f2b(tile[tx][ty + i]);
}

// in-place softmax over rows of 1024 bf16 (one block per row)
__global__ __launch_bounds__(256) void softmax_rows(unsigned short* __restrict__ S) {
  const int tid = threadIdx.x;
  unsigned short* p = S + (long)blockIdx.x * 1024;
  float v[4];
  float m = -3.0e38f;
#pragma unroll
  for (int i = 0; i < 4; i++) { v[i] = b2f(p[tid + 256 * i]); m = fmaxf(m, v[i]); }
#pragma unroll
  for (int o = 1; o < 64; o <<= 1) m = fmaxf(m, __shfl_xor(m, o));
  __shared__ float rm[4], rsum[4];
  const int lane = tid & 63, wave = tid >> 6;
  if (lane == 0) rm[wave] = m;
  __syncthreads();
  m = fmaxf(fmaxf(rm[0], rm[1]), fmaxf(rm[2], rm[3]));
  float s = 0.f;
#pragma unroll
  for (int i = 0; i < 4; i++) { v[i] = __expf(v[i] - m); s += v[i]; }
#pragma unroll
  for (int o = 1; o < 64; o <<= 1) s += __shfl_xor(s, o);
  if (lane == 0) rsum[wave] = s;
  __syncthreads();
  s = rsum[0] + rsum[1] + rsum[2] + rsum[3];
  const float inv = 1.f / s;
#pragma unroll
  for (int i = 0; i < 4; i++) p[tid + 256 * i] = f2b(v[i] * inv);
}

// LayerNorm over rows of 512 f32; Y (f32, optional) and Yb (bf16, optional).
// X and Y may alias (in-place): reads of the row complete before writes.
__global__ __launch_bounds__(256) void layernorm_rows(
    const float* X, const float* __restrict__ g,
    const float* __restrict__ b, float* Y,
    unsigned short* __restrict__ Yb) {
  const int tid = threadIdx.x;
  const long row = blockIdx.x;
  const float* x = X + row * 512;
  float v0 = x[tid], v1 = x[tid + 256];
  float s1 = v0 + v1;
  float s2 = v0 * v0 + v1 * v1;
#pragma unroll
  for (int o = 1; o < 64; o <<= 1) {
    s1 += __shfl_xor(s1, o);
    s2 += __shfl_xor(s2, o);
  }
  __shared__ float r1[4], r2[4];
  const int lane = tid & 63, wave = tid >> 6;
  if (lane == 0) { r1[wave] = s1; r2[wave] = s2; }
  __syncthreads();
  s1 = r1[0] + r1[1] + r1[2] + r1[3];
  s2 = r2[0] + r2[1] + r2[2] + r2[3];
  const float mu = s1 * (1.f / 512.f);
  const float var = s2 * (1.f / 512.f) - mu * mu;
  const float rs = rsqrtf(var + 1e-5f);
  float y0 = (v0 - mu) * rs * g[tid] + b[tid];
  float y1 = (v1 - mu) * rs * g[tid + 256] + b[tid + 256];
  if (Y) { Y[row * 512 + tid] = y0; Y[row * 512 + tid + 256] = y1; }
  if (Yb) { Yb[row * 512 + tid] = f2b(y0); Yb[row * 512 + tid + 256] = f2b(y1); }
}

// ======================= the GEMM =======================
// C[M,N] = A[M,K] @ B[N,K]^T, bf16 in, fp32 acc. 128x128 tile, BK=32,
// 256 thr = 4 waves in 2x2, each wave 64x64 via 4x4 of mfma_16x16x32_bf16.
// Batched via blockIdx.z: per-matrix offset = (z>>3)*sb + (z&7)*sh  (elements).
// EPI: 0 = bf16 out *scale;
//      1 = f32 out + optional bias[n] + optional res (may ALIAS C, same index);
//      2 = bf16 out, relu(acc + bias[n]).
template <int EPI>
__global__ __launch_bounds__(256, 2) void gemm_bt(
    const unsigned short* __restrict__ A, int lda, long asb, long ash,
    const unsigned short* __restrict__ B, int ldb, long bsb, long bsh,
    void* Cv, int ldc, long csb, long csh,
    int K, float scale,
    const float* __restrict__ bias, const float* res) {
  __shared__ __align__(16) unsigned short As[128 * 32];
  __shared__ __align__(16) unsigned short Bs[128 * 32];
  const int tid = threadIdx.x;
  const int lane = tid & 63;
  const int wave = tid >> 6;
  const int zb = (int)(blockIdx.z >> 3), zh = (int)(blockIdx.z & 7);
  const int m0 = blockIdx.y * 128;
  const int n0 = blockIdx.x * 128;

  const unsigned short* Ab = A + zb * asb + zh * ash + (long)m0 * lda;
  const unsigned short* Bb = B + zb * bsb + zh * bsh + (long)n0 * ldb;

  const int r0 = tid >> 2;           // staging row (0..63)
  const int p0 = (tid & 3) << 3;     // staging 8-elem chunk within BK=32

  f32x4 acc[4][4];
#pragma unroll
  for (int i = 0; i < 4; i++)
#pragma unroll
    for (int j = 0; j < 4; j++) acc[i][j] = (f32x4){0.f, 0.f, 0.f, 0.f};

  const int wm = (wave >> 1) << 6;
  const int wn = (wave & 1) << 6;
  const int fm = lane & 15;
  const int k8 = (lane >> 4) << 3;

  for (int kt = 0; kt < K; kt += 32) {
    __syncthreads();
    async_cp16(Ab + (long)r0 * lda + kt + p0, &As[tid * 8]);
    async_cp16(Ab + (long)(r0 + 64) * lda + kt + p0, &As[2048 + tid * 8]);
    async_cp16(Bb + (long)r0 * ldb + kt + p0, &Bs[tid * 8]);
    async_cp16(Bb + (long)(r0 + 64) * ldb + kt + p0, &Bs[2048 + tid * 8]);
    __syncthreads();

    short8 af[4], bfr[4];
#pragma unroll
    for (int i = 0; i < 4; i++)
      af[i] = *(const short8*)&As[(wm + i * 16 + fm) * 32 + k8];
#pragma unroll
    for (int j = 0; j < 4; j++)
      bfr[j] = *(const short8*)&Bs[(wn + j * 16 + fm) * 32 + k8];
#pragma unroll
    for (int i = 0; i < 4; i++)
#pragma unroll
      for (int j = 0; j < 4; j++)
        acc[i][j] = __builtin_amdgcn_mfma_f32_16x16x32_bf16(af[i], bfr[j], acc[i][j], 0, 0, 0);
  }

  // epilogue: D row=(lane>>4)*4+reg, col=lane&15 within each 16x16 tile
  const long coff = zb * csb + zh * csh;
  const int er = (lane >> 4) << 2;
  const int ec = lane & 15;
#pragma unroll
  for (int i = 0; i < 4; i++) {
#pragma unroll
    for (int j = 0; j < 4; j++) {
      const int gc = n0 + wn + j * 16 + ec;
#pragma unroll
      for (int r = 0; r < 4; r++) {
        const int gr = m0 + wm + i * 16 + er + r;
        const float v = acc[i][j][r];
        const long idx = coff + (long)gr * ldc + gc;
        if constexpr (EPI == 0) {
          ((unsigned short*)Cv)[idx] = f2b(v * scale);
        } else if constexpr (EPI == 1) {
          float o = v;
          if (bias) o += bias[gc];
          if (res) o += res[(long)gr * ldc + gc];
          ((float*)Cv)[idx] = o;
        } else {
          ((unsigned short*)Cv)[idx] = f2b(fmaxf(v + bias[gc], 0.f));
        }
      }
    }
  }
}

// ======================= launch =======================
extern "C" void kernel_launch(void* const* d_in, const int* in_sizes, int n_in,
                              void* d_out, int out_size, void* d_ws, size_t ws_size,
                              hipStream_t stream) {
  const float* x     = (const float*)d_in[0];
  const float* enc   = (const float*)d_in[1];
  const float* ln1_g = (const float*)d_in[10];
  const float* ln1_b = (const float*)d_in[11];
  const float* ln2_g = (const float*)d_in[12];
  const float* ln2_b = (const float*)d_in[13];
  const float* ln3_g = (const float*)d_in[14];
  const float* ln3_b = (const float*)d_in[15];
  const float* ff_b1 = (const float*)d_in[17];
  const float* ff_b2 = (const float*)d_in[19];

  uint8_t* ws = (uint8_t*)d_ws;
  auto US = [&](size_t o) { return (unsigned short*)(ws + o); };
  auto F  = [&](size_t o) { return (float*)(ws + o); };

  const size_t MB = 1ull << 20;
  const size_t SZ_WBIG = 4 * MB, SZ_WFF = 2 * MB;

  // ---- fixed regions (76 MB) ----
  const size_t O_XB = 0, O_ENCB = 8 * MB, O_WT = 16 * MB;  // WT: 36 MB -> 52
  const size_t O_RES = 52 * MB;   // f32 residual chain [8192,512], 16 MB
  const size_t O_XNB = 68 * MB;   // bf16 LN output [8192,512], 8 MB
  auto WT = [&](int i) { return US(O_WT + (size_t)i * SZ_WBIG); };

  // ---- adaptive: P1 (O-buffer, 180 MB) vs P2 (per-head out-proj accum, 116 MB) ----
  const bool bigO = ws_size >= 180 * MB;
  const size_t O_O  = 76 * MB;                         // bf16 [8192,4096], 64 MB (P1)
  const size_t PB   = bigO ? 140 * MB : 76 * MB;       // per-head scratch base
  const size_t O_Qh = PB;                              // bf16 [8192,512], 8 MB
  const size_t O_Kh = PB + 8 * MB;                     // bf16 [8192,512], 8 MB
  const size_t O_VT = PB + 16 * MB;                    // bf16 [512,8192], 8 MB
  const size_t O_S  = PB + 24 * MB;                    // bf16 [8,1024,1024], 16 MB
  const size_t O_H  = 76 * MB;                         // FF hidden bf16 [8192,2048], 32 MB

  const float qsc = 0.21022410381342863f;  // 512^-0.25
  dim3 B256(256);

  // input converts
  cvt_f32_bf16<<<4096, B256, 0, stream>>>((const float4*)x, US(O_XB));
  cvt_f32_bf16<<<4096, B256, 0, stream>>>((const float4*)enc, US(O_ENCB));

  // weight transpose+convert: W[R,C] f32 -> W^T[C,R] bf16
  struct WSpec { const float* s; size_t off; int R, C; };
  const WSpec wspec[10] = {
      {(const float*)d_in[2], O_WT + 0 * SZ_WBIG, 512, 4096},   // sa_wq
      {(const float*)d_in[3], O_WT + 1 * SZ_WBIG, 512, 4096},   // sa_wk
      {(const float*)d_in[4], O_WT + 2 * SZ_WBIG, 512, 4096},   // sa_wv
      {(const float*)d_in[5], O_WT + 3 * SZ_WBIG, 4096, 512},   // sa_wo
      {(const float*)d_in[6], O_WT + 4 * SZ_WBIG, 512, 4096},   // ca_wq
      {(const float*)d_in[7], O_WT + 5 * SZ_WBIG, 512, 4096},   // ca_wk
      {(const float*)d_in[8], O_WT + 6 * SZ_WBIG, 512, 4096},   // ca_wv
      {(const float*)d_in[9], O_WT + 7 * SZ_WBIG, 4096, 512},   // ca_wo
      {(const float*)d_in[16], O_WT + 8 * SZ_WBIG, 512, 2048},  // ff_w1
      {(const float*)d_in[18], O_WT + 8 * SZ_WBIG + SZ_WFF, 2048, 512},  // ff_w2
  };
  for (int i = 0; i < 10; i++)
    wtrans<<<dim3(wspec[i].C / 32, wspec[i].R / 32), B256, 0, stream>>>(
        wspec[i].s, US(wspec[i].off), wspec[i].R, wspec[i].C);

  // ---- attention: loop heads, batch b inside each launch ----
  auto attention = [&](const unsigned short* qsrc, const unsigned short* kvsrc,
                       int wb, const float* resid) {
    for (int h = 0; h < 8; h++) {
      const unsigned short* WqTh = WT(wb + 0) + (size_t)h * 512 * 512;
      const unsigned short* WkTh = WT(wb + 1) + (size_t)h * 512 * 512;
      const unsigned short* WvTh = WT(wb + 2) + (size_t)h * 512 * 512;
      // Qh [8192,512] = qsrc @ WqTh^T * qs        (256 blocks)
      gemm_bt<0><<<dim3(4, 64, 1), B256, 0, stream>>>(
          qsrc, 512, 0, 0, WqTh, 512, 0, 0, US(O_Qh), 512, 0, 0, 512, qsc, nullptr, nullptr);
      // Kh [8192,512]                              (256 blocks)
      gemm_bt<0><<<dim3(4, 64, 1), B256, 0, stream>>>(
          kvsrc, 512, 0, 0, WkTh, 512, 0, 0, US(O_Kh), 512, 0, 0, 512, qsc, nullptr, nullptr);
      // VTh [512,8192] = WvTh @ kvsrc^T  (direct-transposed V projection, 256 blocks)
      gemm_bt<0><<<dim3(64, 4, 1), B256, 0, stream>>>(
          WvTh, 512, 0, 0, kvsrc, 512, 0, 0, US(O_VT), 8192, 0, 0, 512, 1.f, nullptr, nullptr);
      // S[b] = Qh[b] @ Kh[b]^T, z=8               (512 blocks)
      gemm_bt<0><<<dim3(8, 8, 8), B256, 0, stream>>>(
          US(O_Qh), 512, 0, 524288L, US(O_Kh), 512, 0, 524288L,
          US(O_S), 1024, 0, 1048576L, 512, 1.f, nullptr, nullptr);
      softmax_rows<<<8192, B256, 0, stream>>>(US(O_S));
      if (bigO) {
        // O[:, h*512:+512] = S @ VTh^T, z=8       (256 blocks)
        gemm_bt<0><<<dim3(4, 8, 8), B256, 0, stream>>>(
            US(O_S), 1024, 0, 1048576L, US(O_VT), 8192, 0, 1024L,
            US(O_O) + (size_t)h * 512, 4096, 0, 4194304L, 1024, 1.f, nullptr, nullptr);
      } else {
        // Oh -> Qh buffer (Qh dead after QK^T), z=8
        gemm_bt<0><<<dim3(4, 8, 8), B256, 0, stream>>>(
            US(O_S), 1024, 0, 1048576L, US(O_VT), 8192, 0, 1024L,
            US(O_Qh), 512, 0, 524288L, 1024, 1.f, nullptr, nullptr);
        // RES (+)= Oh @ WoT[:, h-slice]^T          (256 blocks; res aliases C for h>0)
        gemm_bt<1><<<dim3(4, 64, 1), B256, 0, stream>>>(
            US(O_Qh), 512, 0, 0, WT(wb + 3) + (size_t)h * 512, 4096, 0, 0,
            F(O_RES), 512, 0, 0, 512, 1.f, nullptr, h == 0 ? resid : F(O_RES));
      }
    }
    if (bigO) {
      // att = O @ Wo^T + resid                     (256 blocks, K=4096)
      gemm_bt<1><<<dim3(4, 64, 1), B256, 0, stream>>>(
          US(O_O), 4096, 0, 0, WT(wb + 3), 4096, 0, 0,
          F(O_RES), 512, 0, 0, 4096, 1.f, nullptr, resid);
    }
  };

  // self-attention + LN1 (RES in-place)
  attention(US(O_XB), US(O_XB), 0, x);
  layernorm_rows<<<8192, B256, 0, stream>>>(F(O_RES), ln1_g, ln1_b, F(O_RES), US(O_XNB));
  // cross-attention + LN2
  attention(US(O_XNB), US(O_ENCB), 4, F(O_RES));
  layernorm_rows<<<8192, B256, 0, stream>>>(F(O_RES), ln2_g, ln2_b, F(O_RES), US(O_XNB));
  // FF: relu(x2 @ w1 + b1) @ w2 + b2 + x2, then LN3 -> d_out
  gemm_bt<2><<<dim3(16, 64, 1), B256, 0, stream>>>(
      US(O_XNB), 512, 0, 0, WT(8), 512, 0, 0,
      US(O_H), 2048, 0, 0, 512, 1.f, ff_b1, nullptr);
  gemm_bt<1><<<dim3(4, 64, 1), B256, 0, stream>>>(
      US(O_H), 2048, 0, 0, US(O_WT + 8 * SZ_WBIG + SZ_WFF), 2048, 0, 0,
      F(O_RES), 512, 0, 0, 2048, 1.f, ff_b2, F(O_RES));
  layernorm_rows<<<8192, B256, 0, stream>>>(F(O_RES), ln3_g, ln3_b, (float*)d_out, nullptr);
}

// Round 4
// 1602.625 us; speedup vs baseline: 2.0524x; 1.2615x over previous
//
#include <hip/hip_runtime.h>
#include <stdint.h>

// ======================= types & helpers =======================
typedef short short8 __attribute__((ext_vector_type(8)));
typedef float f32x4 __attribute__((ext_vector_type(4)));

#define DEVI static __device__ __forceinline__

DEVI float b2f(unsigned short u) {
  union { float f; uint32_t i; } v; v.i = ((uint32_t)u) << 16; return v.f;
}
DEVI unsigned short f2b(float f) {  // RNE f32 -> bf16
  union { float f; uint32_t i; } v; v.f = f;
  uint32_t r = v.i + 0x7FFFu + ((v.i >> 16) & 1u);
  return (unsigned short)(r >> 16);
}

// async global->LDS, 16B per lane (HW: LDS dest = wave base + lane*16)
DEVI void async_cp16(const unsigned short* g, unsigned short* l) {
  __builtin_amdgcn_global_load_lds(
      (const __attribute__((address_space(1))) void*)g,
      (__attribute__((address_space(3))) void*)l, 16, 0, 0);
}

// XCD-locality swizzle: HW dispatches linear block id l (x fastest) round-robin
// over 8 XCDs (XCD ~ l%8). Reassign so z' = l%gz (gz=8 -> all blocks of one
// z land on one XCD); for gz=1 the M-tile y' = l%gy pins row-tiles per XCD.
DEVI void swz(int& bx, int& by, int& bz) {
  const int gx = gridDim.x, gy = gridDim.y, gz = gridDim.z;
  int l = blockIdx.x + gx * (blockIdx.y + gy * blockIdx.z);
  bz = l % gz; l /= gz;
  by = l % gy;
  bx = l / gy;
}

// ======================= kernels =======================

// f32 -> bf16 convert, 4 elems/thread, grid*256*4 == n exactly
__global__ __launch_bounds__(256) void cvt_f32_bf16(
    const float4* __restrict__ src, unsigned short* __restrict__ dst) {
  const int i = blockIdx.x * 256 + threadIdx.x;
  float4 f = src[i];
  uint2 o;
  o.x = (uint32_t)f2b(f.x) | ((uint32_t)f2b(f.y) << 16);
  o.y = (uint32_t)f2b(f.z) | ((uint32_t)f2b(f.w) << 16);
  ((uint2*)dst)[i] = o;
}

// f32 [R,C] -> bf16 [C,R] tiled transpose+convert
__global__ __launch_bounds__(256) void wtrans(
    const float* __restrict__ src, unsigned short* __restrict__ dst, int R, int C) {
  __shared__ float tile[32][33];
  const int tx = threadIdx.x & 31, ty = threadIdx.x >> 5;
  const int c0 = blockIdx.x * 32, r0 = blockIdx.y * 32;
#pragma unroll
  for (int i = 0; i < 32; i += 8)
    tile[ty + i][tx] = src[(long)(r0 + ty + i) * C + c0 + tx];
  __syncthreads();
#pragma unroll
  for (int i = 0; i < 32; i += 8)
    dst[(long)(c0 + ty + i) * R + r0 + tx] = f2b(tile[tx][ty + i]);
}

// in-place softmax over rows of 1024 bf16, one block per row.
// Row assignment swizzled so rows of batch b stay on XCD b (S_b L2-hot).
__global__ __launch_bounds__(256) void softmax_rows(unsigned short* __restrict__ S) {
  const int tid = threadIdx.x;
  const int g8 = gridDim.x >> 3;
  const long row = (long)(blockIdx.x & 7) * g8 + (blockIdx.x >> 3);
  unsigned short* p = S + row * 1024;
  float v[4];
  float m = -3.0e38f;
#pragma unroll
  for (int i = 0; i < 4; i++) { v[i] = b2f(p[tid + 256 * i]); m = fmaxf(m, v[i]); }
#pragma unroll
  for (int o = 1; o < 64; o <<= 1) m = fmaxf(m, __shfl_xor(m, o));
  __shared__ float rm[4], rsum[4];
  const int lane = tid & 63, wave = tid >> 6;
  if (lane == 0) rm[wave] = m;
  __syncthreads();
  m = fmaxf(fmaxf(rm[0], rm[1]), fmaxf(rm[2], rm[3]));
  float s = 0.f;
#pragma unroll
  for (int i = 0; i < 4; i++) { v[i] = __expf(v[i] - m); s += v[i]; }
#pragma unroll
  for (int o = 1; o < 64; o <<= 1) s += __shfl_xor(s, o);
  if (lane == 0) rsum[wave] = s;
  __syncthreads();
  s = rsum[0] + rsum[1] + rsum[2] + rsum[3];
  const float inv = 1.f / s;
#pragma unroll
  for (int i = 0; i < 4; i++) p[tid + 256 * i] = f2b(v[i] * inv);
}

// LayerNorm over rows of 512 f32; Y (f32, optional) and Yb (bf16, optional).
// X and Y may alias (in-place): reads of the row complete before writes.
__global__ __launch_bounds__(256) void layernorm_rows(
    const float* X, const float* __restrict__ g,
    const float* __restrict__ b, float* Y,
    unsigned short* __restrict__ Yb) {
  const int tid = threadIdx.x;
  const long row = blockIdx.x;
  const float* x = X + row * 512;
  float v0 = x[tid], v1 = x[tid + 256];
  float s1 = v0 + v1;
  float s2 = v0 * v0 + v1 * v1;
#pragma unroll
  for (int o = 1; o < 64; o <<= 1) {
    s1 += __shfl_xor(s1, o);
    s2 += __shfl_xor(s2, o);
  }
  __shared__ float r1[4], r2[4];
  const int lane = tid & 63, wave = tid >> 6;
  if (lane == 0) { r1[wave] = s1; r2[wave] = s2; }
  __syncthreads();
  s1 = r1[0] + r1[1] + r1[2] + r1[3];
  s2 = r2[0] + r2[1] + r2[2] + r2[3];
  const float mu = s1 * (1.f / 512.f);
  const float var = s2 * (1.f / 512.f) - mu * mu;
  const float rs = rsqrtf(var + 1e-5f);
  float y0 = (v0 - mu) * rs * g[tid] + b[tid];
  float y1 = (v1 - mu) * rs * g[tid + 256] + b[tid + 256];
  if (Y) { Y[row * 512 + tid] = y0; Y[row * 512 + tid + 256] = y1; }
  if (Yb) { Yb[row * 512 + tid] = f2b(y0); Yb[row * 512 + tid + 256] = f2b(y1); }
}

// ======================= the GEMM =======================
// C[M,N] = A[M,K] @ B[N,K]^T, bf16 in, fp32 acc. 128x128 tile, BK=32,
// 256 thr = 4 waves in 2x2, each wave 64x64 via 4x4 of mfma_16x16x32_bf16.
// Batched via z: per-matrix offset = (z>>3)*sb + (z&7)*sh (elements).
// Block coords are XCD-swizzled (see swz).
// EPI: 0 = bf16 out *scale;
//      1 = f32 out + optional bias[n] + optional res (may ALIAS C, same index);
//      2 = bf16 out, relu(acc + bias[n]).
template <int EPI>
__global__ __launch_bounds__(256, 2) void gemm_bt(
    const unsigned short* __restrict__ A, int lda, long asb, long ash,
    const unsigned short* __restrict__ B, int ldb, long bsb, long bsh,
    void* Cv, int ldc, long csb, long csh,
    int K, float scale,
    const float* __restrict__ bias, const float* res) {
  __shared__ __align__(16) unsigned short As[128 * 32];
  __shared__ __align__(16) unsigned short Bs[128 * 32];
  int bx, by, bz;
  swz(bx, by, bz);
  const int tid = threadIdx.x;
  const int lane = tid & 63;
  const int wave = tid >> 6;
  const int zb = bz >> 3, zh = bz & 7;
  const int m0 = by * 128;
  const int n0 = bx * 128;

  const unsigned short* Ab = A + zb * asb + zh * ash + (long)m0 * lda;
  const unsigned short* Bb = B + zb * bsb + zh * bsh + (long)n0 * ldb;

  const int r0 = tid >> 2;           // staging row (0..63)
  const int p0 = (tid & 3) << 3;     // staging 8-elem chunk within BK=32

  f32x4 acc[4][4];
#pragma unroll
  for (int i = 0; i < 4; i++)
#pragma unroll
    for (int j = 0; j < 4; j++) acc[i][j] = (f32x4){0.f, 0.f, 0.f, 0.f};

  const int wm = (wave >> 1) << 6;
  const int wn = (wave & 1) << 6;
  const int fm = lane & 15;
  const int k8 = (lane >> 4) << 3;

  for (int kt = 0; kt < K; kt += 32) {
    __syncthreads();
    async_cp16(Ab + (long)r0 * lda + kt + p0, &As[tid * 8]);
    async_cp16(Ab + (long)(r0 + 64) * lda + kt + p0, &As[2048 + tid * 8]);
    async_cp16(Bb + (long)r0 * ldb + kt + p0, &Bs[tid * 8]);
    async_cp16(Bb + (long)(r0 + 64) * ldb + kt + p0, &Bs[2048 + tid * 8]);
    __syncthreads();

    short8 af[4], bfr[4];
#pragma unroll
    for (int i = 0; i < 4; i++)
      af[i] = *(const short8*)&As[(wm + i * 16 + fm) * 32 + k8];
#pragma unroll
    for (int j = 0; j < 4; j++)
      bfr[j] = *(const short8*)&Bs[(wn + j * 16 + fm) * 32 + k8];
#pragma unroll
    for (int i = 0; i < 4; i++)
#pragma unroll
      for (int j = 0; j < 4; j++)
        acc[i][j] = __builtin_amdgcn_mfma_f32_16x16x32_bf16(af[i], bfr[j], acc[i][j], 0, 0, 0);
  }

  // epilogue: D row=(lane>>4)*4+reg, col=lane&15 within each 16x16 tile
  const long coff = zb * csb + zh * csh;
  const int er = (lane >> 4) << 2;
  const int ec = lane & 15;
#pragma unroll
  for (int i = 0; i < 4; i++) {
#pragma unroll
    for (int j = 0; j < 4; j++) {
      const int gc = n0 + wn + j * 16 + ec;
#pragma unroll
      for (int r = 0; r < 4; r++) {
        const int gr = m0 + wm + i * 16 + er + r;
        const float v = acc[i][j][r];
        const long idx = coff + (long)gr * ldc + gc;
        if constexpr (EPI == 0) {
          ((unsigned short*)Cv)[idx] = f2b(v * scale);
        } else if constexpr (EPI == 1) {
          float o = v;
          if (bias) o += bias[gc];
          if (res) o += res[(long)gr * ldc + gc];
          ((float*)Cv)[idx] = o;
        } else {
          ((unsigned short*)Cv)[idx] = f2b(fmaxf(v + bias[gc], 0.f));
        }
      }
    }
  }
}

// ======================= launch =======================
extern "C" void kernel_launch(void* const* d_in, const int* in_sizes, int n_in,
                              void* d_out, int out_size, void* d_ws, size_t ws_size,
                              hipStream_t stream) {
  const float* x     = (const float*)d_in[0];
  const float* enc   = (const float*)d_in[1];
  const float* ln1_g = (const float*)d_in[10];
  const float* ln1_b = (const float*)d_in[11];
  const float* ln2_g = (const float*)d_in[12];
  const float* ln2_b = (const float*)d_in[13];
  const float* ln3_g = (const float*)d_in[14];
  const float* ln3_b = (const float*)d_in[15];
  const float* ff_b1 = (const float*)d_in[17];
  const float* ff_b2 = (const float*)d_in[19];

  uint8_t* ws = (uint8_t*)d_ws;
  auto US = [&](size_t o) { return (unsigned short*)(ws + o); };
  auto F  = [&](size_t o) { return (float*)(ws + o); };

  const size_t MB = 1ull << 20;
  const size_t SZ_WBIG = 4 * MB, SZ_WFF = 2 * MB;

  // ---- fixed regions (76 MB) ----
  const size_t O_XB = 0, O_ENCB = 8 * MB, O_WT = 16 * MB;  // WT: 36 MB -> 52
  const size_t O_RES = 52 * MB;   // f32 residual chain [8192,512], 16 MB
  const size_t O_XNB = 68 * MB;   // bf16 LN output [8192,512], 8 MB
  auto WT = [&](int i) { return US(O_WT + (size_t)i * SZ_WBIG); };

  // ---- tiers ----
  // T3 (>=190 MB): 4-head-group batched projections; O aliases Q4 slices.
  // else round-3: per-head, bigO if >=180 MB, else per-head out-proj accum.
  const bool t3   = ws_size >= 190 * MB;
  const bool bigO = !t3 && ws_size >= 180 * MB;
  // T3 regions
  const size_t O_Q4 = 76 * MB, O_K4 = 108 * MB, O_VT4 = 140 * MB, O_S3 = 172 * MB;
  // low-tier regions
  const size_t O_O  = 76 * MB;                       // bf16 [8192,4096], 64 MB (bigO)
  const size_t PB   = bigO ? 140 * MB : 76 * MB;
  const size_t O_Qh = PB, O_Kh = PB + 8 * MB, O_VT = PB + 16 * MB, O_S = PB + 24 * MB;
  const size_t O_H  = 76 * MB;                       // FF hidden bf16 [8192,2048], 32 MB

  const float qsc = 0.21022410381342863f;  // 512^-0.25
  dim3 B256(256);

  // input converts
  cvt_f32_bf16<<<4096, B256, 0, stream>>>((const float4*)x, US(O_XB));
  cvt_f32_bf16<<<4096, B256, 0, stream>>>((const float4*)enc, US(O_ENCB));

  // weight transpose+convert: W[R,C] f32 -> W^T[C,R] bf16
  struct WSpec { const float* s; size_t off; int R, C; };
  const WSpec wspec[10] = {
      {(const float*)d_in[2], O_WT + 0 * SZ_WBIG, 512, 4096},   // sa_wq
      {(const float*)d_in[3], O_WT + 1 * SZ_WBIG, 512, 4096},   // sa_wk
      {(const float*)d_in[4], O_WT + 2 * SZ_WBIG, 512, 4096},   // sa_wv
      {(const float*)d_in[5], O_WT + 3 * SZ_WBIG, 4096, 512},   // sa_wo
      {(const float*)d_in[6], O_WT + 4 * SZ_WBIG, 512, 4096},   // ca_wq
      {(const float*)d_in[7], O_WT + 5 * SZ_WBIG, 512, 4096},   // ca_wk
      {(const float*)d_in[8], O_WT + 6 * SZ_WBIG, 512, 4096},   // ca_wv
      {(const float*)d_in[9], O_WT + 7 * SZ_WBIG, 4096, 512},   // ca_wo
      {(const float*)d_in[16], O_WT + 8 * SZ_WBIG, 512, 2048},  // ff_w1
      {(const float*)d_in[18], O_WT + 8 * SZ_WBIG + SZ_WFF, 2048, 512},  // ff_w2
  };
  for (int i = 0; i < 10; i++)
    wtrans<<<dim3(wspec[i].C / 32, wspec[i].R / 32), B256, 0, stream>>>(
        wspec[i].s, US(wspec[i].off), wspec[i].R, wspec[i].C);

  // ---- T3 attention: 2 groups of 4 heads, batched projections ----
  auto attentionT3 = [&](const unsigned short* qsrc, const unsigned short* kvsrc,
                         int wb, const float* resid) {
    for (int g = 0; g < 2; g++) {
      const size_t wo = (size_t)g * 2048 * 512;  // 4-head weight slice (rows)
      // Q4 [8192,2048] = qsrc @ Wq4^T * qs   (1024 blocks)
      gemm_bt<0><<<dim3(16, 64, 1), B256, 0, stream>>>(
          qsrc, 512, 0, 0, WT(wb + 0) + wo, 512, 0, 0,
          US(O_Q4), 2048, 0, 0, 512, qsc, nullptr, nullptr);
      // K4 [8192,2048]                        (1024 blocks)
      gemm_bt<0><<<dim3(16, 64, 1), B256, 0, stream>>>(
          kvsrc, 512, 0, 0, WT(wb + 1) + wo, 512, 0, 0,
          US(O_K4), 2048, 0, 0, 512, qsc, nullptr, nullptr);
      // VT4 [2048,8192] = Wv4 @ kvsrc^T       (1024 blocks)
      gemm_bt<0><<<dim3(64, 16, 1), B256, 0, stream>>>(
          WT(wb + 2) + wo, 512, 0, 0, kvsrc, 512, 0, 0,
          US(O_VT4), 8192, 0, 0, 512, 1.f, nullptr, nullptr);
      for (int hh = 0; hh < 4; hh++) {
        // S[b] = Q4[b, hh-slice] @ K4[b, hh-slice]^T, z=8 over b (512 blocks)
        gemm_bt<0><<<dim3(8, 8, 8), B256, 0, stream>>>(
            US(O_Q4) + (size_t)hh * 512, 2048, 0, 2097152L,
            US(O_K4) + (size_t)hh * 512, 2048, 0, 2097152L,
            US(O_S3), 1024, 0, 1048576L, 512, 1.f, nullptr, nullptr);
        softmax_rows<<<8192, B256, 0, stream>>>(US(O_S3));
        // O slice = S @ VT4[hh]^T -> overwrites Q4's hh-slice (dead after QK)
        gemm_bt<0><<<dim3(4, 8, 8), B256, 0, stream>>>(
            US(O_S3), 1024, 0, 1048576L,
            US(O_VT4) + (size_t)hh * 512 * 8192, 8192, 0, 1024L,
            US(O_Q4) + (size_t)hh * 512, 2048, 0, 2097152L, 1024, 1.f, nullptr, nullptr);
      }
      // RES (+)= O4 @ WoT[:, g*2048:+2048]^T   (256 blocks, K=2048)
      gemm_bt<1><<<dim3(4, 64, 1), B256, 0, stream>>>(
          US(O_Q4), 2048, 0, 0, WT(wb + 3) + (size_t)g * 2048, 4096, 0, 0,
          F(O_RES), 512, 0, 0, 2048, 1.f, nullptr, g == 0 ? resid : F(O_RES));
    }
  };

  // ---- low-tier attention: per-head (round-3 structure) ----
  auto attentionLo = [&](const unsigned short* qsrc, const unsigned short* kvsrc,
                         int wb, const float* resid) {
    for (int h = 0; h < 8; h++) {
      const unsigned short* WqTh = WT(wb + 0) + (size_t)h * 512 * 512;
      const unsigned short* WkTh = WT(wb + 1) + (size_t)h * 512 * 512;
      const unsigned short* WvTh = WT(wb + 2) + (size_t)h * 512 * 512;
      gemm_bt<0><<<dim3(4, 64, 1), B256, 0, stream>>>(
          qsrc, 512, 0, 0, WqTh, 512, 0, 0, US(O_Qh), 512, 0, 0, 512, qsc, nullptr, nullptr);
      gemm_bt<0><<<dim3(4, 64, 1), B256, 0, stream>>>(
          kvsrc, 512, 0, 0, WkTh, 512, 0, 0, US(O_Kh), 512, 0, 0, 512, qsc, nullptr, nullptr);
      gemm_bt<0><<<dim3(64, 4, 1), B256, 0, stream>>>(
          WvTh, 512, 0, 0, kvsrc, 512, 0, 0, US(O_VT), 8192, 0, 0, 512, 1.f, nullptr, nullptr);
      gemm_bt<0><<<dim3(8, 8, 8), B256, 0, stream>>>(
          US(O_Qh), 512, 0, 524288L, US(O_Kh), 512, 0, 524288L,
          US(O_S), 1024, 0, 1048576L, 512, 1.f, nullptr, nullptr);
      softmax_rows<<<8192, B256, 0, stream>>>(US(O_S));
      if (bigO) {
        gemm_bt<0><<<dim3(4, 8, 8), B256, 0, stream>>>(
            US(O_S), 1024, 0, 1048576L, US(O_VT), 8192, 0, 1024L,
            US(O_O) + (size_t)h * 512, 4096, 0, 4194304L, 1024, 1.f, nullptr, nullptr);
      } else {
        gemm_bt<0><<<dim3(4, 8, 8), B256, 0, stream>>>(
            US(O_S), 1024, 0, 1048576L, US(O_VT), 8192, 0, 1024L,
            US(O_Qh), 512, 0, 524288L, 1024, 1.f, nullptr, nullptr);
        gemm_bt<1><<<dim3(4, 64, 1), B256, 0, stream>>>(
            US(O_Qh), 512, 0, 0, WT(wb + 3) + (size_t)h * 512, 4096, 0, 0,
            F(O_RES), 512, 0, 0, 512, 1.f, nullptr, h == 0 ? resid : F(O_RES));
      }
    }
    if (bigO) {
      gemm_bt<1><<<dim3(4, 64, 1), B256, 0, stream>>>(
          US(O_O), 4096, 0, 0, WT(wb + 3), 4096, 0, 0,
          F(O_RES), 512, 0, 0, 4096, 1.f, nullptr, resid);
    }
  };

  auto attention = [&](const unsigned short* q, const unsigned short* kv, int wb,
                       const float* r) {
    if (t3) attentionT3(q, kv, wb, r); else attentionLo(q, kv, wb, r);
  };

  // self-attention + LN1 (RES in-place)
  attention(US(O_XB), US(O_XB), 0, x);
  layernorm_rows<<<8192, B256, 0, stream>>>(F(O_RES), ln1_g, ln1_b, F(O_RES), US(O_XNB));
  // cross-attention + LN2
  attention(US(O_XNB), US(O_ENCB), 4, F(O_RES));
  layernorm_rows<<<8192, B256, 0, stream>>>(F(O_RES), ln2_g, ln2_b, F(O_RES), US(O_XNB));
  // FF: relu(x2 @ w1 + b1) @ w2 + b2 + x2, then LN3 -> d_out
  gemm_bt<2><<<dim3(16, 64, 1), B256, 0, stream>>>(
      US(O_XNB), 512, 0, 0, WT(8), 512, 0, 0,
      US(O_H), 2048, 0, 0, 512, 1.f, ff_b1, nullptr);
  gemm_bt<1><<<dim3(4, 64, 1), B256, 0, stream>>>(
      US(O_H), 2048, 0, 0, US(O_WT + 8 * SZ_WBIG + SZ_WFF), 2048, 0, 0,
      F(O_RES), 512, 0, 0, 2048, 1.f, ff_b2, F(O_RES));
  layernorm_rows<<<8192, B256, 0, stream>>>(F(O_RES), ln3_g, ln3_b, (float*)d_out, nullptr);
}

// Round 6
// 1350.571 us; speedup vs baseline: 2.4355x; 1.1866x over previous
//
#include <hip/hip_runtime.h>
#include <stdint.h>

// ======================= types & helpers =======================
typedef short short8 __attribute__((ext_vector_type(8)));
typedef float f32x4 __attribute__((ext_vector_type(4)));

#define DEVI static __device__ __forceinline__

DEVI float b2f(unsigned short u) {
  union { float f; uint32_t i; } v; v.i = ((uint32_t)u) << 16; return v.f;
}
DEVI unsigned short f2b(float f) {  // RNE f32 -> bf16
  union { float f; uint32_t i; } v; v.f = f;
  uint32_t r = v.i + 0x7FFFu + ((v.i >> 16) & 1u);
  return (unsigned short)(r >> 16);
}

// async global->LDS, 16B per lane (HW: LDS dest = wave base + lane*16)
DEVI void async_cp16(const unsigned short* g, unsigned short* l) {
  __builtin_amdgcn_global_load_lds(
      (const __attribute__((address_space(1))) void*)g,
      (__attribute__((address_space(3))) void*)l, 16, 0, 0);
}

// XCD-locality swizzle: HW round-robins linear block id l over 8 XCDs
// (XCD ~ l%8). Reassign so z' = l%gz (8|gz -> all blocks of one z on one
// XCD); for gz=1 the M-tile y' = l%gy pins row-tiles per XCD.
DEVI void swz(int& bx, int& by, int& bz) {
  const int gx = gridDim.x, gy = gridDim.y, gz = gridDim.z;
  int l = blockIdx.x + gx * (blockIdx.y + gy * blockIdx.z);
  bz = l % gz; l /= gz;
  by = l % gy;
  bx = l / gy;
}

// ======================= kernels =======================

// f32 -> bf16 convert, 4 elems/thread, grid*256*4 == n exactly
__global__ __launch_bounds__(256) void cvt_f32_bf16(
    const float4* __restrict__ src, unsigned short* __restrict__ dst) {
  const int i = blockIdx.x * 256 + threadIdx.x;
  float4 f = src[i];
  uint2 o;
  o.x = (uint32_t)f2b(f.x) | ((uint32_t)f2b(f.y) << 16);
  o.y = (uint32_t)f2b(f.z) | ((uint32_t)f2b(f.w) << 16);
  ((uint2*)dst)[i] = o;
}

// f32 [R,C] -> bf16 [C,R] tiled transpose+convert
__global__ __launch_bounds__(256) void wtrans(
    const float* __restrict__ src, unsigned short* __restrict__ dst, int R, int C) {
  __shared__ float tile[32][33];
  const int tx = threadIdx.x & 31, ty = threadIdx.x >> 5;
  const int c0 = blockIdx.x * 32, r0 = blockIdx.y * 32;
#pragma unroll
  for (int i = 0; i < 32; i += 8)
    tile[ty + i][tx] = src[(long)(r0 + ty + i) * C + c0 + tx];
  __syncthreads();
#pragma unroll
  for (int i = 0; i < 32; i += 8)
    dst[(long)(c0 + ty + i) * R + r0 + tx] = f2b(tile[tx][ty + i]);
}

// in-place softmax over rows of 1024 bf16, one block per row.
// S is [NZ][1024][1024]; block bx handles z = bx%NZ, r = bx/NZ so that
// XCD (= bx%8 = z%8 since 8|NZ) matches the XCD that wrote S_z (= b).
__global__ __launch_bounds__(256) void softmax_rows(
    unsigned short* __restrict__ S, int NZ) {
  const int tid = threadIdx.x;
  const int bx = blockIdx.x;
  const long z = bx % NZ, r = bx / NZ;
  unsigned short* p = S + (z * 1024 + r) * 1024;
  float v[4];
  float m = -3.0e38f;
#pragma unroll
  for (int i = 0; i < 4; i++) { v[i] = b2f(p[tid + 256 * i]); m = fmaxf(m, v[i]); }
#pragma unroll
  for (int o = 1; o < 64; o <<= 1) m = fmaxf(m, __shfl_xor(m, o));
  __shared__ float rm[4], rsum[4];
  const int lane = tid & 63, wave = tid >> 6;
  if (lane == 0) rm[wave] = m;
  __syncthreads();
  m = fmaxf(fmaxf(rm[0], rm[1]), fmaxf(rm[2], rm[3]));
  float s = 0.f;
#pragma unroll
  for (int i = 0; i < 4; i++) { v[i] = __expf(v[i] - m); s += v[i]; }
#pragma unroll
  for (int o = 1; o < 64; o <<= 1) s += __shfl_xor(s, o);
  if (lane == 0) rsum[wave] = s;
  __syncthreads();
  s = rsum[0] + rsum[1] + rsum[2] + rsum[3];
  const float inv = 1.f / s;
#pragma unroll
  for (int i = 0; i < 4; i++) p[tid + 256 * i] = f2b(v[i] * inv);
}

// LayerNorm over rows of 512 f32; Y (f32, optional) and Yb (bf16, optional).
// X and Y may alias (in-place): reads of the row complete before writes.
__global__ __launch_bounds__(256) void layernorm_rows(
    const float* X, const float* __restrict__ g,
    const float* __restrict__ b, float* Y,
    unsigned short* __restrict__ Yb) {
  const int tid = threadIdx.x;
  const long row = blockIdx.x;
  const float* x = X + row * 512;
  float v0 = x[tid], v1 = x[tid + 256];
  float s1 = v0 + v1;
  float s2 = v0 * v0 + v1 * v1;
#pragma unroll
  for (int o = 1; o < 64; o <<= 1) {
    s1 += __shfl_xor(s1, o);
    s2 += __shfl_xor(s2, o);
  }
  __shared__ float r1[4], r2[4];
  const int lane = tid & 63, wave = tid >> 6;
  if (lane == 0) { r1[wave] = s1; r2[wave] = s2; }
  __syncthreads();
  s1 = r1[0] + r1[1] + r1[2] + r1[3];
  s2 = r2[0] + r2[1] + r2[2] + r2[3];
  const float mu = s1 * (1.f / 512.f);
  const float var = s2 * (1.f / 512.f) - mu * mu;
  const float rs = rsqrtf(var + 1e-5f);
  float y0 = (v0 - mu) * rs * g[tid] + b[tid];
  float y1 = (v1 - mu) * rs * g[tid + 256] + b[tid + 256];
  if (Y) { Y[row * 512 + tid] = y0; Y[row * 512 + tid + 256] = y1; }
  if (Yb) { Yb[row * 512 + tid] = f2b(y0); Yb[row * 512 + tid + 256] = f2b(y1); }
}

// ======================= the GEMM =======================
// C[M,N] = A[M,K] @ B[N,K]^T, bf16 in, fp32 acc. 128x128 tile, BK=32,
// 256 thr = 4 waves in 2x2, each wave 64x64 via 4x4 of mfma_16x16x32_bf16.
// Batched via z: per-matrix offset = (z>>3)*sb + (z&7)*sh (elements).
// Block coords are XCD-swizzled (see swz).
// EPI: 0 = bf16 out *scale;
//      1 = f32 out + optional bias[n] + optional res (may ALIAS C, same index);
//      2 = bf16 out, relu(acc + bias[n]).
template <int EPI>
__global__ __launch_bounds__(256, 2) void gemm_bt(
    const unsigned short* __restrict__ A, int lda, long asb, long ash,
    const unsigned short* __restrict__ B, int ldb, long bsb, long bsh,
    void* Cv, int ldc, long csb, long csh,
    int K, float scale,
    const float* __restrict__ bias, const float* res) {
  __shared__ __align__(16) unsigned short As[128 * 32];
  __shared__ __align__(16) unsigned short Bs[128 * 32];
  int bx, by, bz;
  swz(bx, by, bz);
  const int tid = threadIdx.x;
  const int lane = tid & 63;
  const int wave = tid >> 6;
  const int zb = bz >> 3, zh = bz & 7;
  const int m0 = by * 128;
  const int n0 = bx * 128;

  const unsigned short* Ab = A + zb * asb + zh * ash + (long)m0 * lda;
  const unsigned short* Bb = B + zb * bsb + zh * bsh + (long)n0 * ldb;

  const int r0 = tid >> 2;           // staging row (0..63)
  const int p0 = (tid & 3) << 3;     // staging 8-elem chunk within BK=32

  f32x4 acc[4][4];
#pragma unroll
  for (int i = 0; i < 4; i++)
#pragma unroll
    for (int j = 0; j < 4; j++) acc[i][j] = (f32x4){0.f, 0.f, 0.f, 0.f};

  const int wm = (wave >> 1) << 6;
  const int wn = (wave & 1) << 6;
  const int fm = lane & 15;
  const int k8 = (lane >> 4) << 3;

  for (int kt = 0; kt < K; kt += 32) {
    __syncthreads();
    async_cp16(Ab + (long)r0 * lda + kt + p0, &As[tid * 8]);
    async_cp16(Ab + (long)(r0 + 64) * lda + kt + p0, &As[2048 + tid * 8]);
    async_cp16(Bb + (long)r0 * ldb + kt + p0, &Bs[tid * 8]);
    async_cp16(Bb + (long)(r0 + 64) * ldb + kt + p0, &Bs[2048 + tid * 8]);
    __syncthreads();

    short8 af[4], bfr[4];
#pragma unroll
    for (int i = 0; i < 4; i++)
      af[i] = *(const short8*)&As[(wm + i * 16 + fm) * 32 + k8];
#pragma unroll
    for (int j = 0; j < 4; j++)
      bfr[j] = *(const short8*)&Bs[(wn + j * 16 + fm) * 32 + k8];
#pragma unroll
    for (int i = 0; i < 4; i++)
#pragma unroll
      for (int j = 0; j < 4; j++)
        acc[i][j] = __builtin_amdgcn_mfma_f32_16x16x32_bf16(af[i], bfr[j], acc[i][j], 0, 0, 0);
  }

  // epilogue: D row=(lane>>4)*4+reg, col=lane&15 within each 16x16 tile
  const long coff = zb * csb + zh * csh;
  const int er = (lane >> 4) << 2;
  const int ec = lane & 15;
#pragma unroll
  for (int i = 0; i < 4; i++) {
#pragma unroll
    for (int j = 0; j < 4; j++) {
      const int gc = n0 + wn + j * 16 + ec;
#pragma unroll
      for (int r = 0; r < 4; r++) {
        const int gr = m0 + wm + i * 16 + er + r;
        const float v = acc[i][j][r];
        const long idx = coff + (long)gr * ldc + gc;
        if constexpr (EPI == 0) {
          ((unsigned short*)Cv)[idx] = f2b(v * scale);
        } else if constexpr (EPI == 1) {
          float o = v;
          if (bias) o += bias[gc];
          if (res) o += res[(long)gr * ldc + gc];
          ((float*)Cv)[idx] = o;
        } else {
          ((unsigned short*)Cv)[idx] = f2b(fmaxf(v + bias[gc], 0.f));
        }
      }
    }
  }
}

// ======================= launch =======================
extern "C" void kernel_launch(void* const* d_in, const int* in_sizes, int n_in,
                              void* d_out, int out_size, void* d_ws, size_t ws_size,
                              hipStream_t stream) {
  const float* x     = (const float*)d_in[0];
  const float* enc   = (const float*)d_in[1];
  const float* ln1_g = (const float*)d_in[10];
  const float* ln1_b = (const float*)d_in[11];
  const float* ln2_g = (const float*)d_in[12];
  const float* ln2_b = (const float*)d_in[13];
  const float* ln3_g = (const float*)d_in[14];
  const float* ln3_b = (const float*)d_in[15];
  const float* ff_b1 = (const float*)d_in[17];
  const float* ff_b2 = (const float*)d_in[19];

  uint8_t* ws = (uint8_t*)d_ws;
  auto US = [&](size_t o) { return (unsigned short*)(ws + o); };
  auto F  = [&](size_t o) { return (float*)(ws + o); };

  const size_t MB = 1ull << 20;
  const size_t SZ_WBIG = 4 * MB, SZ_WFF = 2 * MB;

  // ---- fixed regions (76 MB) ----
  const size_t O_XB = 0, O_ENCB = 8 * MB, O_WT = 16 * MB;  // WT: 36 MB -> 52
  const size_t O_RES = 52 * MB;   // f32 residual chain [8192,512], 16 MB
  const size_t O_XNB = 68 * MB;   // bf16 LN output [8192,512], 8 MB
  auto WT = [&](int i) { return US(O_WT + (size_t)i * SZ_WBIG); };

  // ---- adaptive head-group size HP: scratch need = 76 + 40*HP MB ----
  int HP = 1;
  for (int c = 8; c >= 1; c >>= 1)
    if (ws_size >= (76 + 40 * (size_t)c) * MB) { HP = c; break; }
  const int NG = 8 / HP;          // groups
  const int NZ = HP * 8;          // batch-z per attention-core launch
  const int LD = HP * 512;        // group row width
  const size_t O_QG  = 76 * MB;                       // bf16 [8192, LD]
  const size_t O_KG  = O_QG + (size_t)HP * 8 * MB;    // bf16 [8192, LD]
  const size_t O_VTG = O_KG + (size_t)HP * 8 * MB;    // bf16 [LD, 8192]
  const size_t O_SG  = O_VTG + (size_t)HP * 8 * MB;   // bf16 [NZ,1024,1024]
  const size_t O_H   = 76 * MB;   // FF hidden bf16 [8192,2048] (attn scratch dead)

  const float qsc = 0.21022410381342863f;  // 512^-0.25
  dim3 B256(256);

  // input converts
  cvt_f32_bf16<<<4096, B256, 0, stream>>>((const float4*)x, US(O_XB));
  cvt_f32_bf16<<<4096, B256, 0, stream>>>((const float4*)enc, US(O_ENCB));

  // weight transpose+convert: W[R,C] f32 -> W^T[C,R] bf16
  struct WSpec { const float* s; size_t off; int R, C; };
  const WSpec wspec[10] = {
      {(const float*)d_in[2], O_WT + 0 * SZ_WBIG, 512, 4096},   // sa_wq
      {(const float*)d_in[3], O_WT + 1 * SZ_WBIG, 512, 4096},   // sa_wk
      {(const float*)d_in[4], O_WT + 2 * SZ_WBIG, 512, 4096},   // sa_wv
      {(const float*)d_in[5], O_WT + 3 * SZ_WBIG, 4096, 512},   // sa_wo
      {(const float*)d_in[6], O_WT + 4 * SZ_WBIG, 512, 4096},   // ca_wq
      {(const float*)d_in[7], O_WT + 5 * SZ_WBIG, 512, 4096},   // ca_wk
      {(const float*)d_in[8], O_WT + 6 * SZ_WBIG, 512, 4096},   // ca_wv
      {(const float*)d_in[9], O_WT + 7 * SZ_WBIG, 4096, 512},   // ca_wo
      {(const float*)d_in[16], O_WT + 8 * SZ_WBIG, 512, 2048},  // ff_w1
      {(const float*)d_in[18], O_WT + 8 * SZ_WBIG + SZ_WFF, 2048, 512},  // ff_w2
  };
  for (int i = 0; i < 10; i++)
    wtrans<<<dim3(wspec[i].C / 32, wspec[i].R / 32), B256, 0, stream>>>(
        wspec[i].s, US(wspec[i].off), wspec[i].R, wspec[i].C);

  // ---- attention: NG groups of HP heads; attention core batched z=NZ ----
  // z decomposition everywhere: z>>3 = head-in-group hh, z&7 = batch b (=XCD).
  auto attention = [&](const unsigned short* qsrc, const unsigned short* kvsrc,
                       int wb, const float* resid) {
    for (int g = 0; g < NG; g++) {
      const size_t woff = (size_t)g * LD * 512;  // weight row-slice offset
      // QG [8192,LD] = qsrc @ Wq_slice^T * qs       (HP*256 blocks)
      gemm_bt<0><<<dim3(HP * 4, 64, 1), B256, 0, stream>>>(
          qsrc, 512, 0, 0, WT(wb + 0) + woff, 512, 0, 0,
          US(O_QG), LD, 0, 0, 512, qsc, nullptr, nullptr);
      // KG [8192,LD]
      gemm_bt<0><<<dim3(HP * 4, 64, 1), B256, 0, stream>>>(
          kvsrc, 512, 0, 0, WT(wb + 1) + woff, 512, 0, 0,
          US(O_KG), LD, 0, 0, 512, qsc, nullptr, nullptr);
      // VTG [LD,8192] = Wv_slice @ kvsrc^T (direct-transposed V)
      gemm_bt<0><<<dim3(64, HP * 4, 1), B256, 0, stream>>>(
          WT(wb + 2) + woff, 512, 0, 0, kvsrc, 512, 0, 0,
          US(O_VTG), 8192, 0, 0, 512, 1.f, nullptr, nullptr);
      // S[z] = Q[b, hh] @ K[b, hh]^T, z = hh*8+b    (NZ*64 blocks)
      gemm_bt<0><<<dim3(8, 8, NZ), B256, 0, stream>>>(
          US(O_QG), LD, 512L, (long)1024 * LD,
          US(O_KG), LD, 512L, (long)1024 * LD,
          US(O_SG), 1024, 8388608L, 1048576L, 512, 1.f, nullptr, nullptr);
      softmax_rows<<<NZ * 1024, B256, 0, stream>>>(US(O_SG), NZ);
      // O[z] = S[z] @ VT[hh, b-cols]^T -> overwrites QG (dead)  (NZ*32 blocks)
      // BUGFIX r5->r6: bsh was 0, dropping the per-batch token offset into
      // VTG's columns (b*1024); every batch read batch 0's V.
      gemm_bt<0><<<dim3(4, 8, NZ), B256, 0, stream>>>(
          US(O_SG), 1024, 8388608L, 1048576L,
          US(O_VTG), 8192, 4194304L, 1024L,
          US(O_QG), LD, 512L, (long)1024 * LD, 1024, 1.f, nullptr, nullptr);
      // RES (+)= O @ Wo[:, g-slice]^T               (256 blocks, K=LD)
      gemm_bt<1><<<dim3(4, 64, 1), B256, 0, stream>>>(
          US(O_QG), LD, 0, 0, WT(wb + 3) + (size_t)g * LD, 4096, 0, 0,
          F(O_RES), 512, 0, 0, LD, 1.f, nullptr, g == 0 ? resid : F(O_RES));
    }
  };

  // self-attention + LN1 (RES in-place)
  attention(US(O_XB), US(O_XB), 0, x);
  layernorm_rows<<<8192, B256, 0, stream>>>(F(O_RES), ln1_g, ln1_b, F(O_RES), US(O_XNB));
  // cross-attention + LN2
  attention(US(O_XNB), US(O_ENCB), 4, F(O_RES));
  layernorm_rows<<<8192, B256, 0, stream>>>(F(O_RES), ln2_g, ln2_b, F(O_RES), US(O_XNB));
  // FF: relu(x2 @ w1 + b1) @ w2 + b2 + x2, then LN3 -> d_out
  gemm_bt<2><<<dim3(16, 64, 1), B256, 0, stream>>>(
      US(O_XNB), 512, 0, 0, WT(8), 512, 0, 0,
      US(O_H), 2048, 0, 0, 512, 1.f, ff_b1, nullptr);
  gemm_bt<1><<<dim3(4, 64, 1), B256, 0, stream>>>(
      US(O_H), 2048, 0, 0, US(O_WT + 8 * SZ_WBIG + SZ_WFF), 2048, 0, 0,
      F(O_RES), 512, 0, 0, 2048, 1.f, ff_b2, F(O_RES));
  layernorm_rows<<<8192, B256, 0, stream>>>(F(O_RES), ln3_g, ln3_b, (float*)d_out, nullptr);
}